// Round 8
// baseline (882.543 us; speedup 1.0000x reference)
//
#include <hip/hip_runtime.h>

// ContrastiveLoss: normalize->fp8 e4m3 -> MX-fp8 MFMA GEMM (A @ B^T, scales=1)
// 128x128 tile, BK=128, K=1024 (8 steps), 2 blocks/CU, fused mask/row-reduce
// epilogue -> final scalar reduce.  N=8192, D=1024. Output: f32 scalar.

constexpr int N = 8192;
constexpr int D = 1024;

typedef int i32x4 __attribute__((ext_vector_type(4)));
typedef int i32x8 __attribute__((ext_vector_type(8)));
typedef float f32x4 __attribute__((ext_vector_type(4)));

// f32 -> OCP e4m3fn, RNE. Inputs are normalized (|x|<=1): no saturation path.
static __device__ inline unsigned int f2fp8(float x) {
  unsigned int u = __float_as_uint(x);
  unsigned int sgn = (u >> 24) & 0x80u;
  float a = __uint_as_float(u & 0x7fffffffu);
  unsigned int bits;
  if (a < 0.015625f) {  // < 2^-6: subnormal quantum 2^-9 (rounds to 0..8)
    bits = (unsigned int)__float2int_rn(a * 512.0f);
  } else {
    unsigned int v = __float_as_uint(a);
    unsigned int e = v >> 23;  // 121..127
    unsigned int m = v & 0x7fffffu;
    unsigned int mr = (m + 0x7ffffu + ((m >> 20) & 1u)) >> 20;  // RNE->3 bits
    bits = ((e - 120u) << 3) + mr;  // mr==8 carries into exponent correctly
  }
  return sgn | bits;
}

// ---------------- normalize: fp32 row -> L2-normalized fp8 row --------------
__global__ __launch_bounds__(256) void normalize_kernel(
    const float* __restrict__ in_col, const float* __restrict__ in_row,
    unsigned int* __restrict__ out_col, unsigned int* __restrict__ out_row,
    unsigned int* __restrict__ zeroBase) {
  // zero lossG/hasG (64 KB) exactly: 64 blocks x 256 thr x 4 B
  if (blockIdx.x < 64) zeroBase[blockIdx.x * 256 + threadIdx.x] = 0u;

  int r = blockIdx.x * 4 + (threadIdx.x >> 6);
  int lane = threadIdx.x & 63;
  const float* in =
      (r < N) ? in_col + (size_t)r * D : in_row + (size_t)(r - N) * D;
  unsigned int* out =
      ((r < N) ? out_col : out_row) + (size_t)(r < N ? r : r - N) * (D / 4);
  float4 v[4];
  float s = 0.f;
#pragma unroll
  for (int c = 0; c < 4; c++) {
    v[c] = ((const float4*)in)[lane + c * 64];
    s += v[c].x * v[c].x + v[c].y * v[c].y + v[c].z * v[c].z + v[c].w * v[c].w;
  }
#pragma unroll
  for (int off = 32; off >= 1; off >>= 1) s += __shfl_xor(s, off, 64);
  float inv = 1.0f / sqrtf(s + 1e-12f);
#pragma unroll
  for (int c = 0; c < 4; c++) {
    unsigned int u = f2fp8(v[c].x * inv) | (f2fp8(v[c].y * inv) << 8) |
                     (f2fp8(v[c].z * inv) << 16) | (f2fp8(v[c].w * inv) << 24);
    out[lane + c * 64] = u;  // 4 fp8 bytes, coalesced
  }
}

// ---------------- fused MX-fp8 GEMM + loss epilogue -------------------------
// 256 thr = 4 waves (2x2). Tile 128x128, K-step 128 fp8 (128 B/row).
// LDS 64 KB: A dbuf 2x16 KB, B dbuf 2x16 KB. Chunk swizzle ch^=row&7
// (16B chunks, 8/row) on stage-source + frag-read (involution, both sides).
// 8 K-steps; stage t+1 before compute t; one __syncthreads per step; MFMA
// burst (~16x K=128) is long enough to hide the barrier's vmcnt drain.
__global__ __launch_bounds__(256, 2) void loss_kernel(
    const unsigned char* __restrict__ An, const unsigned char* __restrict__ Bn,
    const int* __restrict__ tc, const int* __restrict__ tr,
    float* __restrict__ lossG, int* __restrict__ hasG) {
  __shared__ char lds[65536];  // A [0,32768), B [32768,65536)

  const int tid = threadIdx.x;
  const int lane = tid & 63;
  const int wid = tid >> 6;
  const int wr = wid >> 1;  // 0..1 -> 64 rows
  const int wc = wid & 1;   // 0..1 -> 64 cols

  // XCD map: xcd owns j-panels [8x,8x+8) forever (B 1 MB L2-pinned); the
  // ~64 concurrent blocks per XCD share an 8-panel A window (1 MB).
  const int bid = blockIdx.x;  // 4096 = 8 xcd * (64 i * 8 j)
  const int xcd = bid & 7, s = bid >> 3;
  const int iBase = (s >> 3) * 128;
  const int jBase = (xcd * 8 + (s & 7)) * 128;

  // fragment read addressing: row=lane&15, k-window=(lane>>4)*32 bytes
  const int frow = lane & 15;
  const int cg = lane >> 4;
  const int klo = ((2 * cg) ^ (frow & 7)) * 16;      // swizzled chunk, k 0..15
  const int khi = ((2 * cg + 1) ^ (frow & 7)) * 16;  // k 16..31
  int rowA[4], rowB[4];
#pragma unroll
  for (int f = 0; f < 4; f++) rowA[f] = (wr * 64 + f * 16 + frow) * 128;
#pragma unroll
  for (int f = 0; f < 4; f++)
    rowB[f] = 32768 + (wc * 64 + f * 16 + frow) * 128;

  // staging: thread t -> local row t>>3 (+32 per instr), chunk t&7;
  // source chunk pre-swizzled so linear LDS dest + swizzled read match.
  const int srow = tid >> 3;
  const int schunk = (tid & 7) ^ ((tid >> 3) & 7);
  const unsigned char* aS[4];
  const unsigned char* bS[4];
#pragma unroll
  for (int i = 0; i < 4; i++) {
    aS[i] = An + (size_t)(iBase + i * 32 + srow) * D + schunk * 16;
    bS[i] = Bn + (size_t)(jBase + i * 32 + srow) * D + schunk * 16;
  }

#define GLDS(g, l)                                                        \
  __builtin_amdgcn_global_load_lds(                                       \
      (const __attribute__((address_space(1))) void*)(g),                 \
      (__attribute__((address_space(3))) void*)(l), 16, 0, 0)

#define STAGE(st, P)                                                      \
  do {                                                                    \
    _Pragma("unroll") for (int i = 0; i < 4; i++)                         \
        GLDS(aS[i] + (st) * 128, lds + (P)*16384 + i * 4096 + wid * 1024);\
    _Pragma("unroll") for (int i = 0; i < 4; i++)                         \
        GLDS(bS[i] + (st) * 128,                                          \
             lds + 32768 + (P)*16384 + i * 4096 + wid * 1024);            \
  } while (0)

  f32x4 acc[4][4];
#pragma unroll
  for (int a = 0; a < 4; a++)
#pragma unroll
    for (int b = 0; b < 4; b++) acc[a][b] = (f32x4){0.f, 0.f, 0.f, 0.f};

  STAGE(0, 0);
  __syncthreads();

#pragma unroll
  for (int t = 0; t < 8; t++) {
    const int P = t & 1;
    if (t < 7) STAGE(t + 1, P ^ 1);
    i32x8 af[4], bf[4];
#pragma unroll
    for (int f = 0; f < 4; f++) {
      i32x4 lo = *(const i32x4*)(lds + P * 16384 + rowA[f] + klo);
      i32x4 hi = *(const i32x4*)(lds + P * 16384 + rowA[f] + khi);
      af[f][0] = lo[0]; af[f][1] = lo[1]; af[f][2] = lo[2]; af[f][3] = lo[3];
      af[f][4] = hi[0]; af[f][5] = hi[1]; af[f][6] = hi[2]; af[f][7] = hi[3];
    }
#pragma unroll
    for (int f = 0; f < 4; f++) {
      i32x4 lo = *(const i32x4*)(lds + P * 16384 + rowB[f] + klo);
      i32x4 hi = *(const i32x4*)(lds + P * 16384 + rowB[f] + khi);
      bf[f][0] = lo[0]; bf[f][1] = lo[1]; bf[f][2] = lo[2]; bf[f][3] = lo[3];
      bf[f][4] = hi[0]; bf[f][5] = hi[1]; bf[f][6] = hi[2]; bf[f][7] = hi[3];
    }
#pragma unroll
    for (int a = 0; a < 4; a++)
#pragma unroll
      for (int b = 0; b < 4; b++)
        acc[a][b] = __builtin_amdgcn_mfma_scale_f32_16x16x128_f8f6f4(
            af[a], bf[b], acc[a][b], 0, 0,  // cbsz=fp8, blgp=fp8
            0, 127, 0, 127);                // scales = 2^0 (e8m0 127)
    __syncthreads();
  }
#undef STAGE
#undef GLDS

  // ---- epilogue: mask + per-row reduce + sparse atomics ----
  // C/D layout (shape-determined): col = lane&15, row = (lane>>4)*4 + reg
  int trj[4];
#pragma unroll
  for (int f = 0; f < 4; f++) trj[f] = tr[jBase + wc * 64 + f * 16 + frow];

#pragma unroll
  for (int a = 0; a < 4; a++) {
#pragma unroll
    for (int r = 0; r < 4; r++) {
      const int i = iBase + wr * 64 + a * 16 + (lane >> 4) * 4 + r;
      const int tci = tc[i];
      float v = 0.f;
      bool hasp = false;
#pragma unroll
      for (int b = 0; b < 4; b++) {
        float s2 = acc[a][b][r];
        if (tci == trj[b]) {
          if (s2 < 1.0f - 1e-5f) { v += 1.0f - s2; hasp = true; }
        } else if (s2 > 0.5f) {
          v += s2;
        }
      }
#pragma unroll
      for (int off = 1; off < 16; off <<= 1) v += __shfl_xor(v, off, 16);
      unsigned long long m = __ballot(hasp);
      bool rowHas = ((m >> ((lane >> 4) * 16)) & 0xFFFFull) != 0;
      if ((lane & 15) == 0) {
        if (v != 0.f) atomicAdd(&lossG[i], v);
        if (rowHas) atomicOr(&hasG[i], 1);
      }
    }
  }
}

// ---------------- final scalar reduce ---------------------------------------
__global__ __launch_bounds__(1024) void finalize_kernel(
    const float* __restrict__ lossG, const int* __restrict__ hasG,
    float* __restrict__ out) {
  int tid = threadIdx.x;
  float s = 0.f;
  for (int i = tid; i < N; i += 1024)
    if (hasG[i]) s += lossG[i];
#pragma unroll
  for (int off = 32; off >= 1; off >>= 1) s += __shfl_xor(s, off, 64);
  __shared__ float w16[16];
  if ((tid & 63) == 0) w16[tid >> 6] = s;
  __syncthreads();
  if (tid == 0) {
    float t = 0.f;
#pragma unroll
    for (int w = 0; w < 16; w++) t += w16[w];
    out[0] = t / (float)N;
  }
}

extern "C" void kernel_launch(void* const* d_in, const int* in_sizes, int n_in,
                              void* d_out, int out_size, void* d_ws, size_t ws_size,
                              hipStream_t stream) {
  const float* in_col = (const float*)d_in[0];
  const int* tcol = (const int*)d_in[1];
  const float* in_row = (const float*)d_in[2];
  const int* trow = (const int*)d_in[3];
  float* out = (float*)d_out;

  char* ws = (char*)d_ws;
  float* lossG = (float*)ws;               // N f32
  int* hasG = (int*)(ws + (size_t)N * 4);  // N i32
  unsigned char* colN = (unsigned char*)(ws + (size_t)N * 8);  // N*D fp8
  unsigned char* rowN = colN + (size_t)N * D;                  // N*D fp8

  normalize_kernel<<<(2 * N) / 4, 256, 0, stream>>>(
      in_col, in_row, (unsigned int*)colN, (unsigned int*)rowN,
      (unsigned int*)ws);
  loss_kernel<<<4096, 256, 0, stream>>>(colN, rowN, tcol, trow, lossG, hasG);
  finalize_kernel<<<1, 1024, 0, stream>>>(lossG, hasG, out);
}